// Round 5
// baseline (251.937 us; speedup 1.0000x reference)
//
#include <hip/hip_runtime.h>
#include <hip/hip_bf16.h>
#include <stdint.h>
#include <stddef.h>

#define L_SEQ   2048
#define DM      2048
#define NH      32
#define DH      64
#define QSCALE  0.02209708691207961f   // 1/sqrt(2048)
#define QS2     0.0318793579f          // log2(e)/sqrt(2048): scores become log2-domain
#define MAT_N   (L_SEQ * DM)           // 4M elements per 2048x2048 matrix

typedef __bf16  bf16x8 __attribute__((ext_vector_type(8)));
typedef float   f32x4  __attribute__((ext_vector_type(4)));
typedef __hip_bfloat16 bf16;

#if __has_builtin(__builtin_amdgcn_exp2f)
#define EXP2F(x) __builtin_amdgcn_exp2f(x)
#else
#define EXP2F(x) __expf((x) * 0.6931471805599453f)
#endif

__device__ __forceinline__ void gl_lds16(const bf16* g, bf16* l) {
    __builtin_amdgcn_global_load_lds(
        (const __attribute__((address_space(1))) unsigned int*)g,
        (__attribute__((address_space(3))) unsigned int*)l,
        16, 0, 0);
}

// ---------------- fp32 -> bf16 conversion ----------------
__device__ __forceinline__ void conv8s(const float* src, bf16* dst, int i, float sc) {
    float4 a = *(const float4*)(src + i);
    float4 b = *(const float4*)(src + i + 4);
    union { bf16 h[8]; uint4 u; } pk;
    pk.h[0] = __float2bfloat16(a.x * sc); pk.h[1] = __float2bfloat16(a.y * sc);
    pk.h[2] = __float2bfloat16(a.z * sc); pk.h[3] = __float2bfloat16(a.w * sc);
    pk.h[4] = __float2bfloat16(b.x * sc); pk.h[5] = __float2bfloat16(b.y * sc);
    pk.h[6] = __float2bfloat16(b.z * sc); pk.h[7] = __float2bfloat16(b.w * sc);
    *(uint4*)(dst + i) = pk.u;
}

// Wq is pre-scaled by QS2 during conversion (scores come out in log2 domain).
__global__ __launch_bounds__(256)
void convert4_kernel(const float* __restrict__ s0, const float* __restrict__ s1,
                     const float* __restrict__ s2, const float* __restrict__ s3,
                     bf16* __restrict__ d0, bf16* __restrict__ d1,
                     bf16* __restrict__ d2, bf16* __restrict__ d3)
{
    const float* s; bf16* d; float sc = 1.0f;
    switch (blockIdx.y) {
        case 0:  s = s0; d = d0; break;
        case 1:  s = s1; d = d1; sc = QS2; break;
        case 2:  s = s2; d = d2; break;
        default: s = s3; d = d3; break;
    }
    const int i = (blockIdx.x * 256 + threadIdx.x) * 8;   // grid.x=2048 -> exact 4M
    conv8s(s, d, i, sc);
}

// Wo with column permutation k' = h*64+d  <-  k = d*32+h (fallback path only).
__global__ __launch_bounds__(256)
void convert_wo_perm_kernel(const float* __restrict__ s, bf16* __restrict__ d)
{
    const int t   = blockIdx.x * 256 + threadIdx.x;   // 0..524287
    const int row = t >> 8;                           // 256 threads per 2048-row
    const int k0  = (t & 255) * 8;
    const float* sr = s + (size_t)row * DM;
    union { bf16 h[8]; uint4 u; } pk;
#pragma unroll
    for (int j = 0; j < 8; ++j) {
        const int kp = k0 + j;
        const int k  = ((kp & 63) << 5) | (kp >> 6);  // d*32 + h
        pk.h[j] = __float2bfloat16(sr[k]);
    }
    *(uint4*)(d + (size_t)row * DM + k0) = pk.u;
}

// ======================= fused QKV: 256^2 tile, 8 waves, 2-phase counted-vmcnt ==================
// Round-2 schedule + two round-5 tweaks:
//   (1) B-resident XCD mapping: all 8 blocks sharing a B panel (same nt) land on one XCD
//       (bid%8), so each B K-slice is fetched once per chip, not once per XCD.
//   (2) late vmcnt: the counted wait for tile t+1 moves AFTER the second MFMA cluster
//       (still before the barrier) -> ~300 extra cycles of load-latency tolerance.
// Blocks 192..255 (when grid = 256) perform the Wo permute-convert on idle CUs.
__global__ __launch_bounds__(512)
void qkv8_gemm_kernel(const bf16* __restrict__ Xb,
                      const bf16* __restrict__ Wq, const float* __restrict__ bq,
                      const bf16* __restrict__ Wk, const float* __restrict__ bk,
                      const bf16* __restrict__ Wv, const float* __restrict__ bv,
                      bf16* __restrict__ Qws, bf16* __restrict__ Kws, bf16* __restrict__ Vws,
                      const float* __restrict__ WoSrc, bf16* __restrict__ WobDst)
{
    __shared__ bf16 lds[2 * 32768];   // 128 KiB: buf c at c*32768; A halves @0,8192; B halves @16384,24576

    const int bid = blockIdx.x;
    const int tid  = threadIdx.x;

    if (bid >= 192) {
        // ---- Wo permute-convert on otherwise-idle CUs (only when grid = 256) ----
        const int t = (bid - 192) * 512 + tid;        // 0..32767
        const int row = t >> 4;                       // 2048 rows, 16 threads/row
        const int k0base = (t & 15) * 128;
        const float* sr = WoSrc + (size_t)row * DM;
        bf16* dr = WobDst + (size_t)row * DM;
        for (int i = 0; i < 16; ++i) {
            const int k0 = k0base + i * 8;
            union { bf16 h[8]; uint4 u; } pk;
#pragma unroll
            for (int j = 0; j < 8; ++j) {
                const int kp = k0 + j;
                const int k  = ((kp & 63) << 5) | (kp >> 6);  // d*32 + h
                pk.h[j] = __float2bfloat16(sr[k]);
            }
            *(uint4*)(dr + k0) = pk.u;
        }
        return;
    }

    // B-resident mapping: XCD x owns nt in {3x, 3x+1, 3x+2}; all 8 mt-blocks of an nt
    // share that XCD's L2 (B slice fetched once/XCD; A slice shared by 3 blocks).
    const int x   = bid & 7;          // XCD (bid%8 round-robin assumption)
    const int idx = bid >> 3;         // 0..23 within XCD
    const int mt  = idx / 3;          // 0..7
    const int nt  = 3 * x + (idx - mt * 3);   // 0..23
    const int m0  = mt << 8;
    const int ng0 = nt << 8;          // fused n offset
    const int z   = ng0 >> 11;        // 0:Q 1:K 2:V (block-uniform)
    const int n0  = ng0 & 2047;
    const bf16*  W    = (z == 0) ? Wq : (z == 1) ? Wk : Wv;
    const float* bias = (z == 0) ? bq : (z == 1) ? bk : bv;

    const int lane = tid & 63;
    const int wave = tid >> 6;        // 0..7
    const int wm   = wave >> 2;       // 0..1  (m half)
    const int wn   = wave & 3;        // 0..3  (n quarter)
    const int grp8 = (lane >> 4) * 8;
    const int grp4 = (lane >> 4) * 4;
    const int l15  = lane & 15;
    const int axor = (l15 & 7) << 3;  // element-XOR for swizzled fragment reads

    const int scol = ((tid & 7) * 8) ^ (((tid >> 3) & 7) << 3);
    const bf16* gb[8];
    int loff[8];
#pragma unroll
    for (int e = 0; e < 8; ++e) {
        const int hh  = e >> 1;                       // 0,1 = A halves; 2,3 = B halves
        const int row = (e & 1) * 64 + (tid >> 3);    // row within 128-row half
        loff[e] = hh * 8192 + (e & 1) * 4096 + tid * 8;   // elements
        if (hh < 2) {
            gb[e] = Xb + (size_t)(m0 + hh * 128 + row) * DM + scol;
        } else {
            const int nn   = n0 + (hh - 2) * 128 + row;           // head-major output col
            const int brow = ((nn & 63) << 5) | (nn >> 6);        // original W row d*32+h
            gb[e] = W + (size_t)brow * DM + scol;
        }
    }

    const bool swap  = (z == 2);                      // V: compute C^T via operand swap
    const int  aside = swap ? 16384 : 0;
    const int  bside = swap ? 0 : 16384;
    const bf16* fa0 = lds + aside + wm * 8192 + l15 * 64;
    const bf16* fb0 = lds + bside + (wn >> 1) * 8192 + ((wn & 1) * 64 + l15) * 64;

    f32x4 acc[8][4];
    const f32x4 zero = {0.f, 0.f, 0.f, 0.f};
#pragma unroll
    for (int i = 0; i < 8; ++i)
#pragma unroll
        for (int j = 0; j < 4; ++j) acc[i][j] = zero;

#pragma unroll
    for (int e = 0; e < 8; ++e) gl_lds16(gb[e],      lds + loff[e]);
#pragma unroll
    for (int e = 0; e < 8; ++e) gl_lds16(gb[e] + 64, lds + 32768 + loff[e]);
    asm volatile("s_waitcnt vmcnt(8)" ::: "memory");
    asm volatile("s_barrier" ::: "memory");

    for (int t = 0; t < 32; ++t) {
        const int cb = (t & 1) << 15;                 // buffer element offset
        const bf16* fa = fa0 + cb;
        const bf16* fb = fb0 + cb;
        const int c0 = grp8 ^ axor;                   // ks=0 swizzled col
        const int c1 = (32 + grp8) ^ axor;            // ks=1 swizzled col

        bf16x8 af[8], bfr[4];
#pragma unroll
        for (int i = 0; i < 8; ++i) af[i] = *(const bf16x8*)(fa + i * 1024 + c0);
#pragma unroll
        for (int j = 0; j < 4; ++j) bfr[j] = *(const bf16x8*)(fb + j * 1024 + c0);
        asm volatile("s_barrier" ::: "memory");
        __builtin_amdgcn_s_setprio(1);
#pragma unroll
        for (int i = 0; i < 8; ++i)
#pragma unroll
            for (int j = 0; j < 4; ++j)
                acc[i][j] = __builtin_amdgcn_mfma_f32_16x16x32_bf16(af[i], bfr[j], acc[i][j], 0, 0, 0);
        __builtin_amdgcn_s_setprio(0);

#pragma unroll
        for (int i = 0; i < 8; ++i) af[i] = *(const bf16x8*)(fa + i * 1024 + c1);
#pragma unroll
        for (int j = 0; j < 4; ++j) bfr[j] = *(const bf16x8*)(fb + j * 1024 + c1);
        asm volatile("s_waitcnt lgkmcnt(0)" ::: "memory");  // all my reads of buf[t&1] done
        asm volatile("s_barrier" ::: "memory");             // everyone's reads done
        if (t + 2 < 32) {
            const int kb2 = (t + 2) << 6;
#pragma unroll
            for (int e = 0; e < 8; ++e)
                gl_lds16(gb[e] + kb2, lds + cb + loff[e]);  // tile t+2 -> freed buffer
        }
        __builtin_amdgcn_s_setprio(1);
#pragma unroll
        for (int i = 0; i < 8; ++i)
#pragma unroll
            for (int j = 0; j < 4; ++j)
                acc[i][j] = __builtin_amdgcn_mfma_f32_16x16x32_bf16(af[i], bfr[j], acc[i][j], 0, 0, 0);
        __builtin_amdgcn_s_setprio(0);
        __builtin_amdgcn_sched_barrier(0);                  // keep MFMA above the wait
        if (t + 2 < 32) {
            asm volatile("s_waitcnt vmcnt(8)" ::: "memory"); // late wait: tile t+1 landed
        } else if (t == 30) {
            asm volatile("s_waitcnt vmcnt(0)" ::: "memory");
        }
        asm volatile("s_barrier" ::: "memory");             // tile t+1 visible to all waves
    }

    if (z == 0) {
#pragma unroll
        for (int j = 0; j < 4; ++j) {
            const int np = n0 + wn * 64 + j * 16 + l15;
            const float bb = bias[((np & 63) << 5) | (np >> 6)] * QS2;
            const size_t base = ((size_t)(np >> 6) * L_SEQ) * DH + (np & 63);
#pragma unroll
            for (int i = 0; i < 8; ++i)
#pragma unroll
                for (int r = 0; r < 4; ++r) {
                    const int m = m0 + wm * 128 + i * 16 + grp4 + r;
                    Qws[base + (size_t)m * DH] = __float2bfloat16(acc[i][j][r] + bb);
                }
        }
    } else if (z == 1) {
#pragma unroll
        for (int j = 0; j < 4; ++j) {
            const int np = n0 + wn * 64 + j * 16 + l15;
            const float bb = bias[((np & 63) << 5) | (np >> 6)];
            const size_t base = ((size_t)(np >> 6) * L_SEQ) * DH + (np & 63);
#pragma unroll
            for (int i = 0; i < 8; ++i)
#pragma unroll
                for (int r = 0; r < 4; ++r) {
                    const int m = m0 + wm * 128 + i * 16 + grp4 + r;
                    Kws[base + (size_t)m * DH] = __float2bfloat16(acc[i][j][r] + bb);
                }
        }
    } else {
#pragma unroll
        for (int i = 0; i < 8; ++i)
#pragma unroll
            for (int r = 0; r < 4; ++r) {
                const int np = n0 + wm * 128 + i * 16 + grp4 + r;
                const float bb = bias[((np & 63) << 5) | (np >> 6)];
#pragma unroll
                for (int j = 0; j < 4; ++j) {
                    const int mcol = m0 + wn * 64 + j * 16 + l15;
                    Vws[(size_t)np * L_SEQ + mcol] = __float2bfloat16(acc[i][j][r] + bb);
                }
            }
    }
}

// ========== out-projection: monolithic 128^2 tile, K=2048, 512 threads, bias fused ==========
// Counted-vmcnt double-buffer schedule with the round-5 late-wait reorder.
__global__ __launch_bounds__(512)
void out_fused_kernel(const bf16* __restrict__ A,   // Attn [l][h*64+d] bf16
                      const bf16* __restrict__ Wo,  // Wob, k'-permuted bf16
                      const float* __restrict__ bo,
                      float* __restrict__ out)
{
    __shared__ bf16 lds[2 * 16384];   // 64 KiB: buf c at c*16384; A tile @0, B tile @8192

    const int m0 = blockIdx.y * 128, n0 = blockIdx.x * 128;
    const int tid  = threadIdx.x;
    const int lane = tid & 63;
    const int wave = tid >> 6;        // 0..7
    const int wm   = wave >> 1;       // 0..3  (32-row slice)
    const int wn   = wave & 1;        // 0..1  (64-col slice)
    const int grp8 = (lane >> 4) * 8;
    const int grp4 = (lane >> 4) * 4;
    const int l15  = lane & 15;
    const int axor = (l15 & 7) << 3;

    const bf16* gb[4]; int loff[4];
#pragma unroll
    for (int e = 0; e < 4; ++e) {
        const int idx = (e & 1) * 512 + tid;          // 0..1023
        const int row = idx >> 3;                     // 0..127
        const int sc  = ((idx & 7) * 8) ^ ((row & 7) << 3);
        if (e < 2) { gb[e] = A  + (size_t)(m0 + row) * DM + sc; loff[e] = idx * 8; }
        else       { gb[e] = Wo + (size_t)(n0 + row) * DM + sc; loff[e] = 8192 + idx * 8; }
    }

    f32x4 acc[2][4];
    const f32x4 zero = {0.f, 0.f, 0.f, 0.f};
#pragma unroll
    for (int i = 0; i < 2; ++i)
#pragma unroll
        for (int j = 0; j < 4; ++j) acc[i][j] = zero;

#pragma unroll
    for (int e = 0; e < 4; ++e) gl_lds16(gb[e],      lds + loff[e]);
#pragma unroll
    for (int e = 0; e < 4; ++e) gl_lds16(gb[e] + 64, lds + 16384 + loff[e]);
    asm volatile("s_waitcnt vmcnt(4)" ::: "memory");
    asm volatile("s_barrier" ::: "memory");

    for (int t = 0; t < 32; ++t) {
        const int cb = (t & 1) << 14;
        const bf16* fa = lds + cb;
        const bf16* fb = lds + cb + 8192;
        const int c0 = grp8 ^ axor;
        const int c1 = (32 + grp8) ^ axor;

        bf16x8 af[2], bfr[4];
#pragma unroll
        for (int i = 0; i < 2; ++i) af[i]  = *(const bf16x8*)(fa + (wm * 32 + i * 16 + l15) * 64 + c0);
#pragma unroll
        for (int j = 0; j < 4; ++j) bfr[j] = *(const bf16x8*)(fb + (wn * 64 + j * 16 + l15) * 64 + c0);
        asm volatile("s_barrier" ::: "memory");
        __builtin_amdgcn_s_setprio(1);
#pragma unroll
        for (int i = 0; i < 2; ++i)
#pragma unroll
            for (int j = 0; j < 4; ++j)
                acc[i][j] = __builtin_amdgcn_mfma_f32_16x16x32_bf16(af[i], bfr[j], acc[i][j], 0, 0, 0);
        __builtin_amdgcn_s_setprio(0);

#pragma unroll
        for (int i = 0; i < 2; ++i) af[i]  = *(const bf16x8*)(fa + (wm * 32 + i * 16 + l15) * 64 + c1);
#pragma unroll
        for (int j = 0; j < 4; ++j) bfr[j] = *(const bf16x8*)(fb + (wn * 64 + j * 16 + l15) * 64 + c1);
        asm volatile("s_waitcnt lgkmcnt(0)" ::: "memory");   // my reads of buf[t&1] done
        asm volatile("s_barrier" ::: "memory");              // everyone's reads done
        if (t + 2 < 32) {
            const int kadv = (t + 2) * 64;
#pragma unroll
            for (int e = 0; e < 4; ++e) gl_lds16(gb[e] + kadv, lds + cb + loff[e]);
        }
        __builtin_amdgcn_s_setprio(1);
#pragma unroll
        for (int i = 0; i < 2; ++i)
#pragma unroll
            for (int j = 0; j < 4; ++j)
                acc[i][j] = __builtin_amdgcn_mfma_f32_16x16x32_bf16(af[i], bfr[j], acc[i][j], 0, 0, 0);
        __builtin_amdgcn_s_setprio(0);
        __builtin_amdgcn_sched_barrier(0);                   // keep MFMA above the wait
        if (t + 2 < 32) {
            asm volatile("s_waitcnt vmcnt(4)" ::: "memory"); // late wait: tile t+1 landed
        } else if (t == 30) {
            asm volatile("s_waitcnt vmcnt(0)" ::: "memory");
        }
        asm volatile("s_barrier" ::: "memory");              // tile t+1 visible to all waves
    }

#pragma unroll
    for (int j = 0; j < 4; ++j) {
        const int n = n0 + wn * 64 + j * 16 + l15;
        const float bb = bo[n];
#pragma unroll
        for (int i = 0; i < 2; ++i) {
#pragma unroll
            for (int r = 0; r < 4; ++r) {
                const int m = m0 + wm * 32 + i * 16 + grp4 + r;
                out[(size_t)m * DM + n] = acc[i][j][r] + bb;
            }
        }
    }
}

// ============== flash attention: QBLK=128, 8 waves, split-wait K/V pipeline ==============
// Round-2 structure + round-5 split-wait: end-of-iter waits only K(kb+1) (vmcnt(3));
// the V(kb+1) wait (vmcnt(2)+barrier) is deferred until after QK^T+softmax, hiding V's
// load latency under ~600 cycles of compute. Issue order K-then-V everywhere.
__global__ __launch_bounds__(512)
void attention_kernel(const bf16* __restrict__ Qws,  // [h][l][d], pre-scaled by QS2
                      const bf16* __restrict__ Kws,  // [h][l][d]
                      const bf16* __restrict__ Vws,  // [h][d][l]
                      bf16* __restrict__ Attn)       // [l][h*64+d]
{
    __shared__ bf16 lds[24576];   // K dbuf @0 (2x4096), V dbuf @8192 (2x4096), P @16384 (128x64)

    const int h = blockIdx.x, qb = blockIdx.y;
    const int tid  = threadIdx.x;
    const int wave = tid >> 6;       // 0..7
    const int lane = tid & 63;
    const int grp  = lane >> 4;      // 0..3
    const int l15  = lane & 15;
    const int grp8 = grp * 8;
    const int axor = (l15 & 7) << 3;

    const bf16* Qh = Qws + (size_t)h * L_SEQ * DH;
    const bf16* Kh = Kws + (size_t)h * L_SEQ * DH;
    const bf16* Vh = Vws + (size_t)h * DH * L_SEQ;

    const int q0 = qb * 128 + wave * 16;

    bf16x8 qf0 = *(const bf16x8*)(Qh + (size_t)(q0 + l15) * DH + grp8);
    bf16x8 qf1 = *(const bf16x8*)(Qh + (size_t)(q0 + l15) * DH + 32 + grp8);

    // staging: one 16B chunk per thread per matrix per 64-key tile
    const int srow = tid >> 3;                              // 0..63
    const int scol = ((tid & 7) * 8) ^ ((srow & 7) << 3);   // pre-swizzled source col
    const bf16* gK = Kh + (size_t)srow * DH + scol;         // + kb*4096 per tile
    const bf16* gV = Vh + (size_t)srow * L_SEQ + scol;      // + kb*64 per tile
    bf16* ldsK = lds + tid * 8;
    bf16* ldsV = lds + 8192 + tid * 8;
    bf16* Plds = lds + 16384;
    const int prow = (wave * 16 + l15) * 64;                // this lane's P row base

    const f32x4 zero = {0.f, 0.f, 0.f, 0.f};
    f32x4 Oacc[4];
#pragma unroll
    for (int t = 0; t < 4; ++t) Oacc[t] = zero;
    float lsum = 0.f;    // partial softmax denom for q row = l15

    // prologue: stage tiles 0 and 1 (K before V!), wait only K(0)
    gl_lds16(gK,        ldsK);
    gl_lds16(gV,        ldsV);
    gl_lds16(gK + 4096, ldsK + 4096);
    gl_lds16(gV + 64,   ldsV + 4096);
    asm volatile("s_waitcnt vmcnt(3)" ::: "memory");         // K(0) landed
    asm volatile("s_barrier" ::: "memory");

    for (int kb = 0; kb < 32; ++kb) {
        const int cb = (kb & 1) << 12;          // *4096
        const bf16* Kc = lds + cb;
        const bf16* Vc = lds + 8192 + cb;

        // S^T = K Q^T, exp2, pack -> Plds (own rows only)
#pragma unroll
        for (int t = 0; t < 4; ++t) {
            const int rr = (t * 16 + l15) * 64;
            bf16x8 k0 = *(const bf16x8*)(Kc + rr + (grp8 ^ axor));
            bf16x8 k1 = *(const bf16x8*)(Kc + rr + ((32 + grp8) ^ axor));
            f32x4 s = zero;
            __builtin_amdgcn_s_setprio(1);
            s = __builtin_amdgcn_mfma_f32_16x16x32_bf16(k0, qf0, s, 0, 0, 0);
            s = __builtin_amdgcn_mfma_f32_16x16x32_bf16(k1, qf1, s, 0, 0, 0);
            __builtin_amdgcn_s_setprio(0);
            float p0 = EXP2F(s[0]), p1 = EXP2F(s[1]),
                  p2 = EXP2F(s[2]), p3 = EXP2F(s[3]);
            lsum += (p0 + p1) + (p2 + p3);
            union { bf16 hh[4]; uint2 u; } pk;
            pk.hh[0] = __float2bfloat16(p0); pk.hh[1] = __float2bfloat16(p1);
            pk.hh[2] = __float2bfloat16(p2); pk.hh[3] = __float2bfloat16(p3);
            *(uint2*)(&Plds[prow + ((t * 16 + grp * 4) ^ axor)]) = pk.u;
        }
        asm volatile("s_waitcnt lgkmcnt(0)" ::: "memory");   // P writes visible to own reads
        asm volatile("s_waitcnt vmcnt(2)" ::: "memory");     // V(kb) landed (hidden under QK^T)
        asm volatile("s_barrier" ::: "memory");              // all waves see V(kb)

        // O += P V
        __builtin_amdgcn_s_setprio(1);
#pragma unroll
        for (int ks = 0; ks < 2; ++ks) {
            bf16x8 pa = *(const bf16x8*)(&Plds[prow + ((ks * 32 + grp8) ^ axor)]);
#pragma unroll
            for (int t = 0; t < 4; ++t) {
                bf16x8 vb = *(const bf16x8*)(Vc + (t * 16 + l15) * 64 + ((ks * 32 + grp8) ^ axor));
                Oacc[t] = __builtin_amdgcn_mfma_f32_16x16x32_bf16(pa, vb, Oacc[t], 0, 0, 0);
            }
        }
        __builtin_amdgcn_s_setprio(0);

        asm volatile("s_waitcnt lgkmcnt(0)" ::: "memory");   // my K/V/P reads complete
        asm volatile("s_barrier" ::: "memory");              // all waves done with buf[kb&1]
        if (kb + 2 < 32) {
            gl_lds16(gK + (kb + 2) * 4096, ldsK + cb);       // K then V into freed buffer
            gl_lds16(gV + (kb + 2) * 64,   ldsV + cb);
            asm volatile("s_waitcnt vmcnt(3)" ::: "memory"); // K(kb+1) landed only
        } else if (kb == 30) {
            asm volatile("s_waitcnt vmcnt(0)" ::: "memory"); // tail: tile 31 fully landed
        }
        asm volatile("s_barrier" ::: "memory");              // K(kb+1) visible to all waves
    }

    float sden = lsum;
    sden += __shfl_xor(sden, 16, 64);
    sden += __shfl_xor(sden, 32, 64);
    const float inv = 1.f / sden;                  // denom for q row = l15
    float invs[4];
#pragma unroll
    for (int r = 0; r < 4; ++r)
        invs[r] = __shfl(inv, grp * 4 + r, 64);    // denoms for q rows grp*4+r

#pragma unroll
    for (int t = 0; t < 4; ++t) {
#pragma unroll
        for (int r = 0; r < 4; ++r) {
            const int m = q0 + grp * 4 + r;        // Oacc row = q
            const int d = t * 16 + l15;            // Oacc col = d
            Attn[(size_t)m * DM + h * 64 + d] = __float2bfloat16(Oacc[t][r] * invs[r]);
        }
    }
}

extern "C" void kernel_launch(void* const* d_in, const int* in_sizes, int n_in,
                              void* d_out, int out_size, void* d_ws, size_t ws_size,
                              hipStream_t stream)
{
    const float* X  = (const float*)d_in[0];
    const float* Wq = (const float*)d_in[1];
    const float* bq = (const float*)d_in[2];
    const float* Wk = (const float*)d_in[3];
    const float* bk = (const float*)d_in[4];
    const float* Wv = (const float*)d_in[5];
    const float* bv = (const float*)d_in[6];
    const float* Wo = (const float*)d_in[7];
    const float* bo = (const float*)d_in[8];
    float* out = (float*)d_out;

    // workspace layout (8 MB slots):
    bf16* Xb   = (bf16*)d_ws;            // slot 0: X bf16 (reused for Wob only in fallback)
    bf16* Wqb  = Xb  + (size_t)MAT_N;    // slot 1: Wq bf16 (pre-scaled), later reused for Attn
    bf16* Wkb  = Wqb + (size_t)MAT_N;    // slot 2
    bf16* Wvb  = Wkb + (size_t)MAT_N;    // slot 3
    bf16* Qws  = Wvb + (size_t)MAT_N;    // slot 4: [32][2048][64]
    bf16* Kws  = Qws + (size_t)MAT_N;    // slot 5: [32][2048][64]
    bf16* Vws  = Kws + (size_t)MAT_N;    // slot 6: [32][64][2048]
    bf16* Wob7 = Vws + (size_t)MAT_N;    // slot 7: Wob (only if ws_size >= 64 MB)
    bf16* Attn = Wqb;                    // reuse ONLY after qkv consumed Wqb

    const bool big = ws_size >= (size_t)8 * MAT_N * sizeof(bf16);   // 64 MB
    bf16* Wob = big ? Wob7 : Xb;

    convert4_kernel<<<dim3(2048, 4), 256, 0, stream>>>(X, Wq, Wk, Wv, Xb, Wqb, Wkb, Wvb);
    if (big) {
        // blocks 192..255 convert Wo on the CUs the 192-block GEMM leaves idle
        qkv8_gemm_kernel<<<dim3(256), 512, 0, stream>>>(Xb, Wqb, bq, Wkb, bk, Wvb, bv,
                                                        Qws, Kws, Vws, Wo, Wob7);
    } else {
        qkv8_gemm_kernel<<<dim3(192), 512, 0, stream>>>(Xb, Wqb, bq, Wkb, bk, Wvb, bv,
                                                        Qws, Kws, Vws, Wo, Wob);
        convert_wo_perm_kernel<<<dim3(2048), 256, 0, stream>>>(Wo, Wob);  // after qkv: Xb dead
    }
    attention_kernel<<<dim3(32, 16), 512, 0, stream>>>(Qws, Kws, Vws, Attn);
    out_fused_kernel<<<dim3(16, 16), 512, 0, stream>>>(Attn, Wob, bo, out);
}

// Round 6
// 248.918 us; speedup vs baseline: 1.0121x; 1.0121x over previous
//
#include <hip/hip_runtime.h>
#include <hip/hip_bf16.h>
#include <stdint.h>
#include <stddef.h>

#define L_SEQ   2048
#define DM      2048
#define NH      32
#define DH      64
#define QSCALE  0.02209708691207961f   // 1/sqrt(2048)
#define QS2     0.0318793579f          // log2(e)/sqrt(2048): scores become log2-domain
#define MAT_N   (L_SEQ * DM)           // 4M elements per 2048x2048 matrix

typedef __bf16  bf16x8 __attribute__((ext_vector_type(8)));
typedef float   f32x4  __attribute__((ext_vector_type(4)));
typedef __hip_bfloat16 bf16;

#if __has_builtin(__builtin_amdgcn_exp2f)
#define EXP2F(x) __builtin_amdgcn_exp2f(x)
#else
#define EXP2F(x) __expf((x) * 0.6931471805599453f)
#endif

#define BAR()   asm volatile("s_barrier" ::: "memory")
#define LGKM0() asm volatile("s_waitcnt lgkmcnt(0)" ::: "memory")

__device__ __forceinline__ void gl_lds16(const bf16* g, bf16* l) {
    __builtin_amdgcn_global_load_lds(
        (const __attribute__((address_space(1))) unsigned int*)g,
        (__attribute__((address_space(3))) unsigned int*)l,
        16, 0, 0);
}

// ---------------- fp32 -> bf16 conversion ----------------
__device__ __forceinline__ void conv8s(const float* src, bf16* dst, int i, float sc) {
    float4 a = *(const float4*)(src + i);
    float4 b = *(const float4*)(src + i + 4);
    union { bf16 h[8]; uint4 u; } pk;
    pk.h[0] = __float2bfloat16(a.x * sc); pk.h[1] = __float2bfloat16(a.y * sc);
    pk.h[2] = __float2bfloat16(a.z * sc); pk.h[3] = __float2bfloat16(a.w * sc);
    pk.h[4] = __float2bfloat16(b.x * sc); pk.h[5] = __float2bfloat16(b.y * sc);
    pk.h[6] = __float2bfloat16(b.z * sc); pk.h[7] = __float2bfloat16(b.w * sc);
    *(uint4*)(dst + i) = pk.u;
}

// Wq is pre-scaled by QS2 during conversion (scores come out in log2 domain).
__global__ __launch_bounds__(256)
void convert4_kernel(const float* __restrict__ s0, const float* __restrict__ s1,
                     const float* __restrict__ s2, const float* __restrict__ s3,
                     bf16* __restrict__ d0, bf16* __restrict__ d1,
                     bf16* __restrict__ d2, bf16* __restrict__ d3)
{
    const float* s; bf16* d; float sc = 1.0f;
    switch (blockIdx.y) {
        case 0:  s = s0; d = d0; break;
        case 1:  s = s1; d = d1; sc = QS2; break;
        case 2:  s = s2; d = d2; break;
        default: s = s3; d = d3; break;
    }
    const int i = (blockIdx.x * 256 + threadIdx.x) * 8;   // grid.x=2048 -> exact 4M
    conv8s(s, d, i, sc);
}

// Wo with column permutation k' = h*64+d  <-  k = d*32+h (fallback path only).
__global__ __launch_bounds__(256)
void convert_wo_perm_kernel(const float* __restrict__ s, bf16* __restrict__ d)
{
    const int t   = blockIdx.x * 256 + threadIdx.x;   // 0..524287
    const int row = t >> 8;                           // 256 threads per 2048-row
    const int k0  = (t & 255) * 8;
    const float* sr = s + (size_t)row * DM;
    union { bf16 h[8]; uint4 u; } pk;
#pragma unroll
    for (int j = 0; j < 8; ++j) {
        const int kp = k0 + j;
        const int k  = ((kp & 63) << 5) | (kp >> 6);  // d*32 + h
        pk.h[j] = __float2bfloat16(sr[k]);
    }
    *(uint4*)(d + (size_t)row * DM + k0) = pk.u;
}

// ================ fused QKV: 256^2 tile, 8 waves, m201-style 8-phase pipeline ================
// Per iteration = 2 K-tiles (buf0 phases 1-4, buf1 phases 5-8); each phase:
//   {ds_read this phase's fragments; stage ONE half-slot (2 gl_lds); [vmcnt at ph4/ph8];
//    barrier; lgkmcnt(0); setprio(1); 16 MFMA; setprio(0); barrier}
// Half-slot staging schedule (each slot written >=1 phase after the barrier retiring its reads):
//   ph1-3: A1/B0/B1 of tile 2u+1 -> buf1   (consumed phases 5-8 this iteration)
//   ph4-7: A0/A1/B0/B1 of tile 2u+2 -> buf0 (consumed next iteration ph1-4)
//   ph8:   A0 of tile 2u+3 -> buf1
// Counted waits: vmcnt(2) at ph4 (buf1 landed) and ph8 (buf0-next landed); never 0 in-loop.
// B-resident XCD mapping kept (round-5: FETCH 111->53 MB).
// Blocks 192..255 (grid 256) perform the Wo permute-convert on idle CUs.
__global__ __launch_bounds__(512)
void qkv8_gemm_kernel(const bf16* __restrict__ Xb,
                      const bf16* __restrict__ Wq, const float* __restrict__ bq,
                      const bf16* __restrict__ Wk, const float* __restrict__ bk,
                      const bf16* __restrict__ Wv, const float* __restrict__ bv,
                      bf16* __restrict__ Qws, bf16* __restrict__ Kws, bf16* __restrict__ Vws,
                      const float* __restrict__ WoSrc, bf16* __restrict__ WobDst)
{
    __shared__ bf16 lds[2 * 32768];   // buf c at c*32768; half-slots: A0@0 A1@8192 B0@16384 B1@24576

    const int bid = blockIdx.x;
    const int tid  = threadIdx.x;

    if (bid >= 192) {
        // ---- Wo permute-convert on otherwise-idle CUs (only when grid = 256) ----
        const int t = (bid - 192) * 512 + tid;        // 0..32767
        const int row = t >> 4;                       // 2048 rows, 16 threads/row
        const int k0base = (t & 15) * 128;
        const float* sr = WoSrc + (size_t)row * DM;
        bf16* dr = WobDst + (size_t)row * DM;
        for (int i = 0; i < 16; ++i) {
            const int k0 = k0base + i * 8;
            union { bf16 h[8]; uint4 u; } pk;
#pragma unroll
            for (int j = 0; j < 8; ++j) {
                const int kp = k0 + j;
                const int k  = ((kp & 63) << 5) | (kp >> 6);  // d*32 + h
                pk.h[j] = __float2bfloat16(sr[k]);
            }
            *(uint4*)(dr + k0) = pk.u;
        }
        return;
    }

    // B-resident mapping: XCD x owns nt in {3x,3x+1,3x+2}; 8 mt-blocks of an nt share its L2.
    const int x   = bid & 7;
    const int idx = bid >> 3;         // 0..23
    const int mt  = idx / 3;          // 0..7
    const int nt  = 3 * x + (idx - mt * 3);
    const int m0  = mt << 8;
    const int ng0 = nt << 8;
    const int z   = ng0 >> 11;        // 0:Q 1:K 2:V (block-uniform)
    const int n0  = ng0 & 2047;
    const bf16*  W    = (z == 0) ? Wq : (z == 1) ? Wk : Wv;
    const float* bias = (z == 0) ? bq : (z == 1) ? bk : bv;

    const int lane = tid & 63;
    const int wave = tid >> 6;        // 0..7
    const int wm   = wave >> 2;       // 0..1  (m half)
    const int wn   = wave & 3;        // 0..3  (n quarter)
    const int grp8 = (lane >> 4) * 8;
    const int grp4 = (lane >> 4) * 4;
    const int l15  = lane & 15;
    const int axor = (l15 & 7) << 3;

    const int scol = ((tid & 7) * 8) ^ (((tid >> 3) & 7) << 3);
    const bf16* gb[8];
    int loff[8];
#pragma unroll
    for (int e = 0; e < 8; ++e) {
        const int hh  = e >> 1;                       // half-slot: 0=A0 1=A1 2=B0 3=B1
        const int row = (e & 1) * 64 + (tid >> 3);
        loff[e] = hh * 8192 + (e & 1) * 4096 + tid * 8;
        if (hh < 2) {
            gb[e] = Xb + (size_t)(m0 + hh * 128 + row) * DM + scol;
        } else {
            const int nn   = n0 + (hh - 2) * 128 + row;
            const int brow = ((nn & 63) << 5) | (nn >> 6);
            gb[e] = W + (size_t)brow * DM + scol;
        }
    }

    const bool swap  = (z == 2);
    const int  aside = swap ? 16384 : 0;
    const int  bside = swap ? 0 : 16384;
    const bf16* fa0 = lds + aside + wm * 8192 + l15 * 64;
    const bf16* fb0 = lds + bside + (wn >> 1) * 8192 + ((wn & 1) * 64 + l15) * 64;

    f32x4 acc[8][4];
    const f32x4 zero = {0.f, 0.f, 0.f, 0.f};
#pragma unroll
    for (int i = 0; i < 8; ++i)
#pragma unroll
        for (int j = 0; j < 4; ++j) acc[i][j] = zero;

    const int c0 = grp8 ^ axor;
    const int c1 = (32 + grp8) ^ axor;

#define STAGE(hh, tile, bufoff) do { \
        gl_lds16(gb[2*(hh)]     + (tile) * 64, lds + (bufoff) + loff[2*(hh)]); \
        gl_lds16(gb[2*(hh) + 1] + (tile) * 64, lds + (bufoff) + loff[2*(hh)+1]); } while (0)

#define MFMA16(BASE) do { \
        __builtin_amdgcn_s_setprio(1); \
        _Pragma("unroll") \
        for (int i = 0; i < 4; ++i) \
        _Pragma("unroll") \
        for (int j = 0; j < 4; ++j) \
            acc[(BASE) + i][j] = __builtin_amdgcn_mfma_f32_16x16x32_bf16(a[i], b[j], acc[(BASE) + i][j], 0, 0, 0); \
        __builtin_amdgcn_s_setprio(0); } while (0)

    // prologue: tile0 -> buf0, tile1 -> buf1; wait tile0 only
#pragma unroll
    for (int e = 0; e < 8; ++e) gl_lds16(gb[e],      lds + loff[e]);
#pragma unroll
    for (int e = 0; e < 8; ++e) gl_lds16(gb[e] + 64, lds + 32768 + loff[e]);
    asm volatile("s_waitcnt vmcnt(8)" ::: "memory");
    BAR();

    for (int u = 0; u < 16; ++u) {
        const int t0 = 2 * u;
        const bf16* faA = fa0;           const bf16* fbA = fb0;            // buf0
        const bf16* faB = fa0 + 32768;   const bf16* fbB = fb0 + 32768;    // buf1
        bf16x8 a[4], b[4];

        // ---- ph1: buf0, ihalf0, ks0 ----
#pragma unroll
        for (int i = 0; i < 4; ++i) a[i] = *(const bf16x8*)(faA + i * 1024 + c0);
#pragma unroll
        for (int j = 0; j < 4; ++j) b[j] = *(const bf16x8*)(fbA + j * 1024 + c0);
        if (u > 0) STAGE(1, t0 + 1, 32768);
        BAR(); LGKM0();
        MFMA16(0);
        BAR();

        // ---- ph2: buf0, ihalf1, ks0 (B reused from regs) ----
#pragma unroll
        for (int i = 0; i < 4; ++i) a[i] = *(const bf16x8*)(faA + (4 + i) * 1024 + c0);
        if (u > 0) STAGE(2, t0 + 1, 32768);
        BAR(); LGKM0();
        MFMA16(4);
        BAR();

        // ---- ph3: buf0, ihalf0, ks1 ----
#pragma unroll
        for (int i = 0; i < 4; ++i) a[i] = *(const bf16x8*)(faA + i * 1024 + c1);
#pragma unroll
        for (int j = 0; j < 4; ++j) b[j] = *(const bf16x8*)(fbA + j * 1024 + c1);
        if (u > 0) STAGE(3, t0 + 1, 32768);
        BAR(); LGKM0();
        MFMA16(0);
        BAR();

        // ---- ph4: buf0, ihalf1, ks1; stage A0(buf0,next); W2: buf1 ready ----
#pragma unroll
        for (int i = 0; i < 4; ++i) a[i] = *(const bf16x8*)(faA + (4 + i) * 1024 + c1);
        if (u < 15) {
            STAGE(0, t0 + 2, 0);
            asm volatile("s_waitcnt vmcnt(2)" ::: "memory");
        } else {
            asm volatile("s_waitcnt vmcnt(0)" ::: "memory");
        }
        BAR(); LGKM0();
        MFMA16(4);
        BAR();

        // ---- ph5: buf1, ihalf0, ks0 ----
#pragma unroll
        for (int i = 0; i < 4; ++i) a[i] = *(const bf16x8*)(faB + i * 1024 + c0);
#pragma unroll
        for (int j = 0; j < 4; ++j) b[j] = *(const bf16x8*)(fbB + j * 1024 + c0);
        if (u < 15) STAGE(1, t0 + 2, 0);
        BAR(); LGKM0();
        MFMA16(0);
        BAR();

        // ---- ph6: buf1, ihalf1, ks0 ----
#pragma unroll
        for (int i = 0; i < 4; ++i) a[i] = *(const bf16x8*)(faB + (4 + i) * 1024 + c0);
        if (u < 15) STAGE(2, t0 + 2, 0);
        BAR(); LGKM0();
        MFMA16(4);
        BAR();

        // ---- ph7: buf1, ihalf0, ks1 ----
#pragma unroll
        for (int i = 0; i < 4; ++i) a[i] = *(const bf16x8*)(faB + i * 1024 + c1);
#pragma unroll
        for (int j = 0; j < 4; ++j) b[j] = *(const bf16x8*)(fbB + j * 1024 + c1);
        if (u < 15) STAGE(3, t0 + 2, 0);
        BAR(); LGKM0();
        MFMA16(0);
        BAR();

        // ---- ph8: buf1, ihalf1, ks1; stage A0(buf1,t0+3); W1: buf0-next ready ----
#pragma unroll
        for (int i = 0; i < 4; ++i) a[i] = *(const bf16x8*)(faB + (4 + i) * 1024 + c1);
        if (u < 15) {
            STAGE(0, t0 + 3, 32768);
            asm volatile("s_waitcnt vmcnt(2)" ::: "memory");
        }
        BAR(); LGKM0();
        MFMA16(4);
        BAR();
    }
#undef STAGE
#undef MFMA16

    if (z == 0) {
#pragma unroll
        for (int j = 0; j < 4; ++j) {
            const int np = n0 + wn * 64 + j * 16 + l15;
            const float bb = bias[((np & 63) << 5) | (np >> 6)] * QS2;
            const size_t base = ((size_t)(np >> 6) * L_SEQ) * DH + (np & 63);
#pragma unroll
            for (int i = 0; i < 8; ++i)
#pragma unroll
                for (int r = 0; r < 4; ++r) {
                    const int m = m0 + wm * 128 + i * 16 + grp4 + r;
                    Qws[base + (size_t)m * DH] = __float2bfloat16(acc[i][j][r] + bb);
                }
        }
    } else if (z == 1) {
#pragma unroll
        for (int j = 0; j < 4; ++j) {
            const int np = n0 + wn * 64 + j * 16 + l15;
            const float bb = bias[((np & 63) << 5) | (np >> 6)];
            const size_t base = ((size_t)(np >> 6) * L_SEQ) * DH + (np & 63);
#pragma unroll
            for (int i = 0; i < 8; ++i)
#pragma unroll
                for (int r = 0; r < 4; ++r) {
                    const int m = m0 + wm * 128 + i * 16 + grp4 + r;
                    Kws[base + (size_t)m * DH] = __float2bfloat16(acc[i][j][r] + bb);
                }
        }
    } else {
#pragma unroll
        for (int i = 0; i < 8; ++i)
#pragma unroll
            for (int r = 0; r < 4; ++r) {
                const int np = n0 + wm * 128 + i * 16 + grp4 + r;
                const float bb = bias[((np & 63) << 5) | (np >> 6)];
#pragma unroll
                for (int j = 0; j < 4; ++j) {
                    const int mcol = m0 + wn * 64 + j * 16 + l15;
                    Vws[(size_t)np * L_SEQ + mcol] = __float2bfloat16(acc[i][j][r] + bb);
                }
            }
    }
}

// ========== out-projection: monolithic 128^2 tile, K=2048, 512 threads, bias fused ==========
// (round-4 version: counted-vmcnt double-buffer, wait before barrier — frozen.)
__global__ __launch_bounds__(512)
void out_fused_kernel(const bf16* __restrict__ A,   // Attn [l][h*64+d] bf16
                      const bf16* __restrict__ Wo,  // Wob, k'-permuted bf16
                      const float* __restrict__ bo,
                      float* __restrict__ out)
{
    __shared__ bf16 lds[2 * 16384];   // buf c at c*16384; A tile @0, B tile @8192

    const int m0 = blockIdx.y * 128, n0 = blockIdx.x * 128;
    const int tid  = threadIdx.x;
    const int lane = tid & 63;
    const int wave = tid >> 6;        // 0..7
    const int wm   = wave >> 1;       // 0..3  (32-row slice)
    const int wn   = wave & 1;        // 0..1  (64-col slice)
    const int grp8 = (lane >> 4) * 8;
    const int grp4 = (lane >> 4) * 4;
    const int l15  = lane & 15;
    const int axor = (l15 & 7) << 3;

    const bf16* gb[4]; int loff[4];
#pragma unroll
    for (int e = 0; e < 4; ++e) {
        const int idx = (e & 1) * 512 + tid;          // 0..1023
        const int row = idx >> 3;                     // 0..127
        const int sc  = ((idx & 7) * 8) ^ ((row & 7) << 3);
        if (e < 2) { gb[e] = A  + (size_t)(m0 + row) * DM + sc; loff[e] = idx * 8; }
        else       { gb[e] = Wo + (size_t)(n0 + row) * DM + sc; loff[e] = 8192 + idx * 8; }
    }

    f32x4 acc[2][4];
    const f32x4 zero = {0.f, 0.f, 0.f, 0.f};
#pragma unroll
    for (int i = 0; i < 2; ++i)
#pragma unroll
        for (int j = 0; j < 4; ++j) acc[i][j] = zero;

#pragma unroll
    for (int e = 0; e < 4; ++e) gl_lds16(gb[e],      lds + loff[e]);
#pragma unroll
    for (int e = 0; e < 4; ++e) gl_lds16(gb[e] + 64, lds + 16384 + loff[e]);
    asm volatile("s_waitcnt vmcnt(4)" ::: "memory");
    BAR();

    for (int t = 0; t < 32; ++t) {
        const int cb = (t & 1) << 14;
        const bf16* fa = lds + cb;
        const bf16* fb = lds + cb + 8192;
        const int c0 = grp8 ^ axor;
        const int c1 = (32 + grp8) ^ axor;

        bf16x8 af[2], bfr[4];
#pragma unroll
        for (int i = 0; i < 2; ++i) af[i]  = *(const bf16x8*)(fa + (wm * 32 + i * 16 + l15) * 64 + c0);
#pragma unroll
        for (int j = 0; j < 4; ++j) bfr[j] = *(const bf16x8*)(fb + (wn * 64 + j * 16 + l15) * 64 + c0);
        BAR();
        __builtin_amdgcn_s_setprio(1);
#pragma unroll
        for (int i = 0; i < 2; ++i)
#pragma unroll
            for (int j = 0; j < 4; ++j)
                acc[i][j] = __builtin_amdgcn_mfma_f32_16x16x32_bf16(af[i], bfr[j], acc[i][j], 0, 0, 0);
        __builtin_amdgcn_s_setprio(0);

#pragma unroll
        for (int i = 0; i < 2; ++i) af[i]  = *(const bf16x8*)(fa + (wm * 32 + i * 16 + l15) * 64 + c1);
#pragma unroll
        for (int j = 0; j < 4; ++j) bfr[j] = *(const bf16x8*)(fb + (wn * 64 + j * 16 + l15) * 64 + c1);
        LGKM0();
        BAR();
        if (t + 2 < 32) {
            const int kadv = (t + 2) * 64;
#pragma unroll
            for (int e = 0; e < 4; ++e) gl_lds16(gb[e] + kadv, lds + cb + loff[e]);
            asm volatile("s_waitcnt vmcnt(4)" ::: "memory");
        } else if (t == 30) {
            asm volatile("s_waitcnt vmcnt(0)" ::: "memory");
        }
        __builtin_amdgcn_s_setprio(1);
#pragma unroll
        for (int i = 0; i < 2; ++i)
#pragma unroll
            for (int j = 0; j < 4; ++j)
                acc[i][j] = __builtin_amdgcn_mfma_f32_16x16x32_bf16(af[i], bfr[j], acc[i][j], 0, 0, 0);
        __builtin_amdgcn_s_setprio(0);
        BAR();
    }

#pragma unroll
    for (int j = 0; j < 4; ++j) {
        const int n = n0 + wn * 64 + j * 16 + l15;
        const float bb = bo[n];
#pragma unroll
        for (int i = 0; i < 2; ++i) {
#pragma unroll
            for (int r = 0; r < 4; ++r) {
                const int m = m0 + wm * 32 + i * 16 + grp4 + r;
                out[(size_t)m * DM + n] = acc[i][j][r] + bb;
            }
        }
    }
}

// ============== flash attention (round-4 version, frozen): QBLK=128, 8 waves ==============
__global__ __launch_bounds__(512)
void attention_kernel(const bf16* __restrict__ Qws,  // [h][l][d], pre-scaled by QS2
                      const bf16* __restrict__ Kws,  // [h][l][d]
                      const bf16* __restrict__ Vws,  // [h][d][l]
                      bf16* __restrict__ Attn)       // [l][h*64+d]
{
    __shared__ bf16 lds[24576];   // K dbuf @0 (2x4096), V dbuf @8192 (2x4096), P @16384 (128x64)

    const int h = blockIdx.x, qb = blockIdx.y;
    const int tid  = threadIdx.x;
    const int wave = tid >> 6;       // 0..7
    const int lane = tid & 63;
    const int grp  = lane >> 4;      // 0..3
    const int l15  = lane & 15;
    const int grp8 = grp * 8;
    const int axor = (l15 & 7) << 3;

    const bf16* Qh = Qws + (size_t)h * L_SEQ * DH;
    const bf16* Kh = Kws + (size_t)h * L_SEQ * DH;
    const bf16* Vh = Vws + (size_t)h * DH * L_SEQ;

    const int q0 = qb * 128 + wave * 16;

    bf16x8 qf0 = *(const bf16x8*)(Qh + (size_t)(q0 + l15) * DH + grp8);
    bf16x8 qf1 = *(const bf16x8*)(Qh + (size_t)(q0 + l15) * DH + 32 + grp8);

    const int srow = tid >> 3;                              // 0..63
    const int scol = ((tid & 7) * 8) ^ ((srow & 7) << 3);   // pre-swizzled source col
    const bf16* gK = Kh + (size_t)srow * DH + scol;         // + kb*4096 per tile
    const bf16* gV = Vh + (size_t)srow * L_SEQ + scol;      // + kb*64 per tile
    bf16* ldsK = lds + tid * 8;
    bf16* ldsV = lds + 8192 + tid * 8;
    bf16* Plds = lds + 16384;
    const int prow = (wave * 16 + l15) * 64;

    const f32x4 zero = {0.f, 0.f, 0.f, 0.f};
    f32x4 Oacc[4];
#pragma unroll
    for (int t = 0; t < 4; ++t) Oacc[t] = zero;
    float lsum = 0.f;

    gl_lds16(gK,        ldsK);
    gl_lds16(gV,        ldsV);
    gl_lds16(gK + 4096, ldsK + 4096);
    gl_lds16(gV + 64,   ldsV + 4096);
    asm volatile("s_waitcnt vmcnt(2)" ::: "memory");
    BAR();

    for (int kb = 0; kb < 32; ++kb) {
        const int cb = (kb & 1) << 12;          // *4096
        const bf16* Kc = lds + cb;
        const bf16* Vc = lds + 8192 + cb;

#pragma unroll
        for (int t = 0; t < 4; ++t) {
            const int rr = (t * 16 + l15) * 64;
            bf16x8 k0 = *(const bf16x8*)(Kc + rr + (grp8 ^ axor));
            bf16x8 k1 = *(const bf16x8*)(Kc + rr + ((32 + grp8) ^ axor));
            f32x4 s = zero;
            __builtin_amdgcn_s_setprio(1);
            s = __builtin_amdgcn_mfma_f32_16x16x32_bf16(k0, qf0, s, 0, 0, 0);
            s = __builtin_amdgcn_mfma_f32_16x16x32_bf16(k1, qf1, s, 0, 0, 0);
            __builtin_amdgcn_s_setprio(0);
            float p0 = EXP2F(s[0]), p1 = EXP2F(s[1]),
                  p2 = EXP2F(s[2]), p3 = EXP2F(s[3]);
            lsum += (p0 + p1) + (p2 + p3);
            union { bf16 hh[4]; uint2 u; } pk;
            pk.hh[0] = __float2bfloat16(p0); pk.hh[1] = __float2bfloat16(p1);
            pk.hh[2] = __float2bfloat16(p2); pk.hh[3] = __float2bfloat16(p3);
            *(uint2*)(&Plds[prow + ((t * 16 + grp * 4) ^ axor)]) = pk.u;
        }
        LGKM0();

        __builtin_amdgcn_s_setprio(1);
#pragma unroll
        for (int ks = 0; ks < 2; ++ks) {
            bf16x8 pa = *(const bf16x8*)(&Plds[prow + ((ks * 32 + grp8) ^ axor)]);
#pragma unroll
            for (int t = 0; t < 4; ++t) {
                bf16x8 vb = *(const bf16x8*)(Vc + (t * 16 + l15) * 64 + ((ks * 32 + grp8) ^ axor));
                Oacc[t] = __builtin_amdgcn_mfma_f32_16x16x32_bf16(pa, vb, Oacc[t], 0, 0, 0);
            }
        }
        __builtin_amdgcn_s_setprio(0);

        LGKM0();
        BAR();
        if (kb + 2 < 32) {
            gl_lds16(gK + (kb + 2) * 4096, ldsK + cb);
            gl_lds16(gV + (kb + 2) * 64,   ldsV + cb);
            asm volatile("s_waitcnt vmcnt(2)" ::: "memory");
        } else if (kb == 30) {
            asm volatile("s_waitcnt vmcnt(0)" ::: "memory");
        }
        BAR();
    }

    float sden = lsum;
    sden += __shfl_xor(sden, 16, 64);
    sden += __shfl_xor(sden, 32, 64);
    const float inv = 1.f / sden;
    float invs[4];
#pragma unroll
    for (int r = 0; r < 4; ++r)
        invs[r] = __shfl(inv, grp * 4 + r, 64);

#pragma unroll
    for (int t = 0; t < 4; ++t) {
#pragma unroll
        for (int r = 0; r < 4; ++r) {
            const int m = q0 + grp * 4 + r;
            const int d = t * 16 + l15;
            Attn[(size_t)m * DM + h * 64 + d] = __float2bfloat16(Oacc[t][r] * invs[r]);
        }
    }
}

extern "C" void kernel_launch(void* const* d_in, const int* in_sizes, int n_in,
                              void* d_out, int out_size, void* d_ws, size_t ws_size,
                              hipStream_t stream)
{
    const float* X  = (const float*)d_in[0];
    const float* Wq = (const float*)d_in[1];
    const float* bq = (const float*)d_in[2];
    const float* Wk = (const float*)d_in[3];
    const float* bk = (const float*)d_in[4];
    const float* Wv = (const float*)d_in[5];
    const float* bv = (const float*)d_in[6];
    const float* Wo = (const float*)d_in[7];
    const float* bo = (const float*)d_in[8];
    float* out = (float*)d_out;

    // workspace layout (8 MB slots):
    bf16* Xb   = (bf16*)d_ws;            // slot 0: X bf16 (reused for Wob only in fallback)
    bf16* Wqb  = Xb  + (size_t)MAT_N;    // slot 1: Wq bf16 (pre-scaled), later reused for Attn
    bf16* Wkb  = Wqb + (size_t)MAT_N;    // slot 2
    bf16* Wvb  = Wkb + (size_t)MAT_N;    // slot 3
    bf16* Qws  = Wvb + (size_t)MAT_N;    // slot 4: [32][2048][64]
    bf16* Kws  = Qws + (size_t)MAT_N;    // slot 5: [32][2048][64]
    bf16* Vws  = Kws + (size_t)MAT_N;    // slot 6: [32][64][2048]
    bf16* Wob7 = Vws + (size_t)MAT_N;    // slot 7: Wob (only if ws_size >= 64 MB)
    bf16* Attn = Wqb;                    // reuse ONLY after qkv consumed Wqb

    const bool big = ws_size >= (size_t)8 * MAT_N * sizeof(bf16);   // 64 MB
    bf16* Wob = big ? Wob7 : Xb;

    convert4_kernel<<<dim3(2048, 4), 256, 0, stream>>>(X, Wq, Wk, Wv, Xb, Wqb, Wkb, Wvb);
    if (big) {
        qkv8_gemm_kernel<<<dim3(256), 512, 0, stream>>>(Xb, Wqb, bq, Wkb, bk, Wvb, bv,
                                                        Qws, Kws, Vws, Wo, Wob7);
    } else {
        qkv8_gemm_kernel<<<dim3(192), 512, 0, stream>>>(Xb, Wqb, bq, Wkb, bk, Wvb, bv,
                                                        Qws, Kws, Vws, Wo, Wob);
        convert_wo_perm_kernel<<<dim3(2048), 256, 0, stream>>>(Wo, Wob);
    }
    attention_kernel<<<dim3(32, 16), 512, 0, stream>>>(Qws, Kws, Vws, Attn);
    out_fused_kernel<<<dim3(16, 16), 512, 0, stream>>>(Attn, Wob, bo, out);
}